// Round 4
// baseline (265.315 us; speedup 1.0000x reference)
//
#include <hip/hip_runtime.h>

// Attention fwd: x@Wqkv^T -> flash attn -> @Wproj^T.  bf16 MFMA pipeline, fp32 accum.
// B=2 N=2048 C=768 H=12 Dh=64.

typedef __bf16 bf16;
typedef __attribute__((ext_vector_type(8))) __bf16 bf16x8;
typedef __attribute__((ext_vector_type(4))) __bf16 bf16x4;
typedef __attribute__((ext_vector_type(2))) __bf16 bf16x2;
typedef __attribute__((ext_vector_type(4))) float f32x4;

typedef __attribute__((address_space(1))) void gvoid;
typedef __attribute__((address_space(3))) void lvoid;

__device__ __forceinline__ void gload16(const void* g, void* l) {
  __builtin_amdgcn_global_load_lds((gvoid*)g, (lvoid*)l, 16, 0, 0);
}

// ---------------- fp32 -> bf16 conversion (x, W_qkv, W_proj) ----------------
__global__ __launch_bounds__(256) void cvt3(const float* __restrict__ x,
                                            const float* __restrict__ wq,
                                            const float* __restrict__ wp,
                                            bf16* __restrict__ xb,
                                            bf16* __restrict__ wqb,
                                            bf16* __restrict__ wpb) {
  const int N1 = 786432, N2 = 442368, N3 = 147456;  // float4 counts
  int i = blockIdx.x * 256 + threadIdx.x;
  const int stride = gridDim.x * 256;
  const int total = N1 + N2 + N3;
  for (; i < total; i += stride) {
    const float* src; bf16* dst; int j;
    if (i < N1)           { src = x;  dst = xb;  j = i; }
    else if (i < N1 + N2) { src = wq; dst = wqb; j = i - N1; }
    else                  { src = wp; dst = wpb; j = i - N1 - N2; }
    float4 v = ((const float4*)src)[j];
    bf16x4 o = { (bf16)v.x, (bf16)v.y, (bf16)v.z, (bf16)v.w };
    *(bf16x4*)(dst + (long)j * 4) = o;
  }
}

// ---------------- NT GEMM: C[M,N] = A[M,K] * B[N,K]^T, bf16 in, fp32 accum -----
template <typename OutT>
__global__ __launch_bounds__(256) void gemm_nt(const bf16* __restrict__ A,
                                               const bf16* __restrict__ B,
                                               OutT* __restrict__ C,
                                               int K, int lda, int ldb, int ldc,
                                               int mtiles) {
  __shared__ __align__(16) char smem[32768];  // [buf][A 8K | B 8K] x2
  const int tid  = threadIdx.x;
  const int lane = tid & 63;
  const int w    = tid >> 6;
  const int wm   = w >> 1, wn = w & 1;
  const int m0   = (blockIdx.x % mtiles) * 128;
  const int n0   = (blockIdx.x / mtiles) * 128;
  const int nt   = K >> 5;

  f32x4 acc[4][4] = {};

  auto stage = [&](int buf, int t) {
    const int k0 = t << 5;
    char* sA = smem + buf * 16384;
    char* sB = sA + 8192;
#pragma unroll
    for (int i = 0; i < 2; ++i) {
      const int slot = i * 256 + tid;          // 512 chunks of 16B per operand
      const int row  = slot >> 2;              // [0,128)
      const int sc   = (slot & 3) ^ (row & 3); // pre-swizzled source chunk
      gload16(A + (long)(m0 + row) * lda + k0 + sc * 8, sA + slot * 16);
      gload16(B + (long)(n0 + row) * ldb + k0 + sc * 8, sB + slot * 16);
    }
  };

  auto compute = [&](int buf) {
    const char* sA = smem + buf * 16384;
    const char* sB = sA + 8192;
    const int c = lane >> 4;
    bf16x8 a[4], b[4];
#pragma unroll
    for (int mi = 0; mi < 4; ++mi) {
      const int row = wm * 64 + mi * 16 + (lane & 15);
      a[mi] = *(const bf16x8*)(sA + row * 64 + ((c ^ (row & 3)) << 4));
    }
#pragma unroll
    for (int ni = 0; ni < 4; ++ni) {
      const int row = wn * 64 + ni * 16 + (lane & 15);
      b[ni] = *(const bf16x8*)(sB + row * 64 + ((c ^ (row & 3)) << 4));
    }
#pragma unroll
    for (int mi = 0; mi < 4; ++mi)
#pragma unroll
      for (int ni = 0; ni < 4; ++ni)
        acc[mi][ni] = __builtin_amdgcn_mfma_f32_16x16x32_bf16(a[mi], b[ni], acc[mi][ni], 0, 0, 0);
  };

  stage(0, 0);
  __syncthreads();
  for (int t = 0; t < nt; ++t) {
    if (t + 1 < nt) stage((t + 1) & 1, t + 1);
    compute(t & 1);
    __syncthreads();
  }

#pragma unroll
  for (int mi = 0; mi < 4; ++mi)
#pragma unroll
    for (int ni = 0; ni < 4; ++ni)
#pragma unroll
      for (int r = 0; r < 4; ++r) {
        const int row = m0 + wm * 64 + mi * 16 + (lane >> 4) * 4 + r;
        const int col = n0 + wn * 64 + ni * 16 + (lane & 15);
        C[(long)row * ldc + col] = (OutT)acc[mi][ni][r];
      }
}

// ---------------- flash attention fwd ----------------
// grid (64 qtiles x 32 rows, 24 bh); block 256 = 4 waves.
// KV-SPLIT: waves {0,1} process even-interleaved KV tiles, {2,3} odd half;
// private (m,l,O) per half, merged once at the end via LDS (log2-domain).
// Swapped QK^T (S^T = K Q^T, lane owns one q-col -> 2-shuffle softmax),
// in-register P (permuted-k mapping), V reg-staged + paired-b32 swizzled
// scatter transpose into per-half double-buffered LDS.
__global__ __launch_bounds__(256, 5) void attn_fwd(const bf16* __restrict__ qkv,
                                                   bf16* __restrict__ O) {
  __shared__ __align__(16) char Vs[32768];  // [half][buf][ Vt 64d x 128B swizzled ]
  const int tid  = threadIdx.x;
  const int lane = tid & 63;
  const int w    = tid >> 6;
  const int l15  = lane & 15;
  const int l4   = lane >> 4;
  const int hh   = w >> 1;   // kv half
  const int qs   = w & 1;    // q sub-block (16 rows)
  const int b    = blockIdx.y / 12;
  const int h    = blockIdx.y % 12;
  const int q0   = blockIdx.x * 32;
  const unsigned base = (unsigned)b * 2048u * 2304u;  // element offset (fits u32)
  const int h64  = h * 64;
  const unsigned KVSTEP = 128u * 2304u;  // two interleaved halves -> stride 128 rows

  char* Vh = Vs + hh * 16384;

  // Q fragments, pre-scaled by SCALE*log2(e) (exp2-domain softmax)
  bf16x8 qf[2];
  {
    const bf16* qp = qkv + base + (unsigned)(q0 + qs * 16 + l15) * 2304u + h64 + l4 * 8;
#pragma unroll
    for (int kk = 0; kk < 2; ++kk) {
      bf16x8 t = *(const bf16x8*)(qp + kk * 32);
#pragma unroll
      for (int j = 0; j < 8; ++j) qf[kk][j] = (bf16)((float)t[j] * 0.18033688f);
    }
  }

  // K row offsets (A-fragments straight from global; L2/L3-resident)
  unsigned koff[4];
#pragma unroll
  for (int f = 0; f < 4; ++f)
    koff[f] = base + (unsigned)(hh * 64 + f * 16 + l15) * 2304u + 768u + h64 + l4 * 8;

  // V staging: 128 threads/half; thread i -> kv pair p = i&31 (rows 2p,2p+1),
  // d-blocks d80*8 and (d80+4)*8.  Writes bf16x2 pairs (kv contiguous).
  const int ii  = qs * 64 + lane;
  const int p   = ii & 31;
  const int d80 = ii >> 5;  // [0,4)
  unsigned voff = base + (unsigned)(hh * 64 + 2 * p) * 2304u + 1536u + h64 + d80 * 8;

  auto vt_write = [&](char* W, const bf16x8& r0a, const bf16x8& r1a,
                      const bf16x8& r0b, const bf16x8& r1b) {
    const int cw = (p & 3) * 4;
    const int pc = p >> 2;
#pragma unroll
    for (int j = 0; j < 8; ++j) {
      const int d = d80 * 8 + j;
      bf16x2 t = { r0a[j], r1a[j] };
      *(bf16x2*)(W + d * 128 + ((pc ^ (d & 7)) << 4) + cw) = t;
    }
#pragma unroll
    for (int j = 0; j < 8; ++j) {
      const int d = (d80 + 4) * 8 + j;
      bf16x2 t = { r0b[j], r1b[j] };
      *(bf16x2*)(W + d * 128 + ((pc ^ (d & 7)) << 4) + cw) = t;
    }
  };

  float m = -1e30f, lsum = 0.f;
  f32x4 o[4] = {};

  // prologue: stage this half's tile 0 into buf 0
  {
    bf16x8 r0a = *(const bf16x8*)(qkv + voff);
    bf16x8 r0b = *(const bf16x8*)(qkv + voff + 32);
    bf16x8 r1a = *(const bf16x8*)(qkv + voff + 2304);
    bf16x8 r1b = *(const bf16x8*)(qkv + voff + 2304 + 32);
    voff += KVSTEP;
    vt_write(Vh, r0a, r1a, r0b, r1b);
  }
  __syncthreads();

  for (int t = 0; t < 16; ++t) {
    const int buf = t & 1;

    // (a) issue next V tile's global loads early (written after PV)
    bf16x8 nr0a, nr0b, nr1a, nr1b;
    if (t < 15) {
      nr0a = *(const bf16x8*)(qkv + voff);
      nr0b = *(const bf16x8*)(qkv + voff + 32);
      nr1a = *(const bf16x8*)(qkv + voff + 2304);
      nr1b = *(const bf16x8*)(qkv + voff + 2304 + 32);
      voff += KVSTEP;
    }

    // (b) S^T = K Q^T : rows = kv (l4*4+r per 16-frag f), cols = q (l15)
    f32x4 s[4];
#pragma unroll
    for (int f = 0; f < 4; ++f) {
      bf16x8 k0 = *(const bf16x8*)(qkv + koff[f]);
      bf16x8 k1 = *(const bf16x8*)(qkv + koff[f] + 32);
      f32x4 acc = {};
      acc = __builtin_amdgcn_mfma_f32_16x16x32_bf16(k0, qf[0], acc, 0, 0, 0);
      acc = __builtin_amdgcn_mfma_f32_16x16x32_bf16(k1, qf[1], acc, 0, 0, 0);
      s[f] = acc;
      koff[f] += KVSTEP;
    }

    // (c) softmax (exp2 domain): tile max for this lane's q (=l15)
    float tm = s[0][0];
#pragma unroll
    for (int f = 0; f < 4; ++f)
#pragma unroll
      for (int r = 0; r < 4; ++r) tm = fmaxf(tm, s[f][r]);
    tm = fmaxf(tm, __shfl_xor(tm, 16));
    tm = fmaxf(tm, __shfl_xor(tm, 32));

    // defer-max: rescale only when tile max outgrows running max by >8 (2^8 bound)
    if (__any(tm > m + 8.f)) {
      const float mn = fmaxf(m, tm);
      const float alpha = __builtin_amdgcn_exp2f(m - mn);
      m = mn;
      lsum *= alpha;
      f32x4 av;
#pragma unroll
      for (int r = 0; r < 4; ++r) av[r] = __shfl(alpha, l4 * 4 + r);
#pragma unroll
      for (int fd = 0; fd < 4; ++fd) o[fd] *= av;
    }

    // p = 2^(s - m); lane-local partial row-sum
    float rs = 0.f;
#pragma unroll
    for (int f = 0; f < 4; ++f)
#pragma unroll
      for (int r = 0; r < 4; ++r) {
        const float pv = __builtin_amdgcn_exp2f(s[f][r] - m);
        s[f][r] = pv;
        rs += pv;
      }

    // P A-fragments in-register (k-slot j of mfma kk -> kv = (kk*2+(j>>2))*16 + l4*4 + (j&3))
    bf16x8 pa[2];
#pragma unroll
    for (int kk = 0; kk < 2; ++kk)
#pragma unroll
      for (int j = 0; j < 8; ++j)
        pa[kk][j] = (bf16)s[kk * 2 + (j >> 2)][j & 3];

    // (e) O += P V : B-frags from swizzled Vt with the SAME permuted-kv mapping
    const char* Vb = Vh + buf * 8192;
    const int sub = (l4 & 1) * 8;
#pragma unroll
    for (int kk = 0; kk < 2; ++kk) {
      const int cr0 = kk * 4 + (l4 >> 1);
#pragma unroll
      for (int fd = 0; fd < 4; ++fd) {
        const int d = fd * 16 + l15;
        const char* row = Vb + d * 128;
        bf16x4 lo = *(const bf16x4*)(row + ((cr0 ^ (d & 7)) << 4) + sub);
        bf16x4 hi = *(const bf16x4*)(row + (((cr0 + 2) ^ (d & 7)) << 4) + sub);
        bf16x8 vb = __builtin_shufflevector(lo, hi, 0, 1, 2, 3, 4, 5, 6, 7);
        o[fd] = __builtin_amdgcn_mfma_f32_16x16x32_bf16(pa[kk], vb, o[fd], 0, 0, 0);
      }
    }

    // cross-lane row-sum after PV issue (overlaps matrix pipe)
    rs += __shfl_xor(rs, 16);
    rs += __shfl_xor(rs, 32);
    lsum += rs;

    // (d) late-write next V tile into the other buffer
    if (t < 15) vt_write(Vh + (buf ^ 1) * 8192, nr0a, nr1a, nr0b, nr1b);

    __syncthreads();
  }
  // final loop barrier: all PV reads done -> Vs reusable as combine buffer

  // ---- merge halves (log2-domain flash merge) via LDS ----
  float* cb = (float*)Vs;                   // [qs][16 rows][64 d] fp32
  float* cm = (float*)(Vs + 8192);          // m  [qs][16]
  float* cl = (float*)(Vs + 8192 + 128);    // l  [qs][16]
  if (hh == 1) {
#pragma unroll
    for (int fd = 0; fd < 4; ++fd)
#pragma unroll
      for (int r = 0; r < 4; ++r)
        cb[qs * 1024 + (l4 * 4 + r) * 64 + fd * 16 + l15] = o[fd][r];
    if (l4 == 0) { cm[qs * 16 + l15] = m; cl[qs * 16 + l15] = lsum; }
  }
  __syncthreads();
  if (hh == 0) {
    const float mB = cm[qs * 16 + l15];
    const float lB = cl[qs * 16 + l15];
    const float M  = fmaxf(m, mB);
    const float sA = __builtin_amdgcn_exp2f(m - M);
    const float sB = __builtin_amdgcn_exp2f(mB - M);
    const float inv = 1.0f / (lsum * sA + lB * sB);
    const float fAq = sA * inv, fBq = sB * inv;
    f32x4 fA, fB;
#pragma unroll
    for (int r = 0; r < 4; ++r) {
      fA[r] = __shfl(fAq, l4 * 4 + r);
      fB[r] = __shfl(fBq, l4 * 4 + r);
    }
    bf16* op = O + ((long)(b * 2048 + q0 + qs * 16 + l4 * 4)) * 768 + h64 + l15;
#pragma unroll
    for (int fd = 0; fd < 4; ++fd)
#pragma unroll
      for (int r = 0; r < 4; ++r) {
        const float v = o[fd][r] * fA[r] +
                        cb[qs * 1024 + (l4 * 4 + r) * 64 + fd * 16 + l15] * fB[r];
        op[(long)r * 768 + fd * 16] = (bf16)v;
      }
  }
}

// ---------------- launch ----------------
extern "C" void kernel_launch(void* const* d_in, const int* in_sizes, int n_in,
                              void* d_out, int out_size, void* d_ws, size_t ws_size,
                              hipStream_t stream) {
  const float* x  = (const float*)d_in[0];
  const float* wq = (const float*)d_in[1];
  const float* wp = (const float*)d_in[2];
  float* out = (float*)d_out;
  char* ws = (char*)d_ws;

  bf16* xb   = (bf16*)(ws + 0);
  bf16* wqb  = (bf16*)(ws + 6291456);
  bf16* wpb  = (bf16*)(ws + 9830400);
  bf16* qkvb = (bf16*)(ws + 11010048);
  bf16* ob   = (bf16*)(ws + 29884416);

  cvt3<<<dim3(1024), dim3(256), 0, stream>>>(x, wq, wp, xb, wqb, wpb);
  // qkv = x @ Wqkv^T : M=4096 N=2304 K=768
  gemm_nt<bf16><<<dim3(576), dim3(256), 0, stream>>>(xb, wqb, qkvb, 768, 768, 768, 2304, 32);
  attn_fwd<<<dim3(64, 24), dim3(256), 0, stream>>>(qkvb, ob);
  // out = attn_out @ Wproj^T : M=4096 N=768 K=768, fp32 out
  gemm_nt<float><<<dim3(192), dim3(256), 0, stream>>>(ob, wpb, out, 768, 768, 768, 768, 32);
}

// Round 5
// 221.445 us; speedup vs baseline: 1.1981x; 1.1981x over previous
//
#include <hip/hip_runtime.h>

// Attention fwd: x@Wqkv^T -> flash attn -> @Wproj^T.  bf16 MFMA pipeline, fp32 accum.
// B=2 N=2048 C=768 H=12 Dh=64.

typedef __bf16 bf16;
typedef __attribute__((ext_vector_type(8))) __bf16 bf16x8;
typedef __attribute__((ext_vector_type(4))) __bf16 bf16x4;
typedef __attribute__((ext_vector_type(2))) __bf16 bf16x2;
typedef __attribute__((ext_vector_type(4))) float f32x4;

typedef __attribute__((address_space(1))) void gvoid;
typedef __attribute__((address_space(3))) void lvoid;

__device__ __forceinline__ void gload16(const void* g, void* l) {
  __builtin_amdgcn_global_load_lds((gvoid*)g, (lvoid*)l, 16, 0, 0);
}

// ---------------- fp32 -> bf16 conversion (x, W_qkv, W_proj) ----------------
__global__ __launch_bounds__(256) void cvt3(const float* __restrict__ x,
                                            const float* __restrict__ wq,
                                            const float* __restrict__ wp,
                                            bf16* __restrict__ xb,
                                            bf16* __restrict__ wqb,
                                            bf16* __restrict__ wpb) {
  const int N1 = 786432, N2 = 442368, N3 = 147456;  // float4 counts
  int i = blockIdx.x * 256 + threadIdx.x;
  const int stride = gridDim.x * 256;
  const int total = N1 + N2 + N3;
  for (; i < total; i += stride) {
    const float* src; bf16* dst; int j;
    if (i < N1)           { src = x;  dst = xb;  j = i; }
    else if (i < N1 + N2) { src = wq; dst = wqb; j = i - N1; }
    else                  { src = wp; dst = wpb; j = i - N1 - N2; }
    float4 v = ((const float4*)src)[j];
    bf16x4 o = { (bf16)v.x, (bf16)v.y, (bf16)v.z, (bf16)v.w };
    *(bf16x4*)(dst + (long)j * 4) = o;
  }
}

// ---------------- NT GEMM: C[M,N] = A[M,K] * B[N,K]^T, bf16 in, fp32 accum -----
template <typename OutT>
__global__ __launch_bounds__(256) void gemm_nt(const bf16* __restrict__ A,
                                               const bf16* __restrict__ B,
                                               OutT* __restrict__ C,
                                               int K, int lda, int ldb, int ldc,
                                               int mtiles) {
  __shared__ __align__(16) char smem[32768];  // [buf][A 8K | B 8K] x2
  const int tid  = threadIdx.x;
  const int lane = tid & 63;
  const int w    = tid >> 6;
  const int wm   = w >> 1, wn = w & 1;
  const int m0   = (blockIdx.x % mtiles) * 128;
  const int n0   = (blockIdx.x / mtiles) * 128;
  const int nt   = K >> 5;

  f32x4 acc[4][4] = {};

  auto stage = [&](int buf, int t) {
    const int k0 = t << 5;
    char* sA = smem + buf * 16384;
    char* sB = sA + 8192;
#pragma unroll
    for (int i = 0; i < 2; ++i) {
      const int slot = i * 256 + tid;          // 512 chunks of 16B per operand
      const int row  = slot >> 2;              // [0,128)
      const int sc   = (slot & 3) ^ (row & 3); // pre-swizzled source chunk
      gload16(A + (long)(m0 + row) * lda + k0 + sc * 8, sA + slot * 16);
      gload16(B + (long)(n0 + row) * ldb + k0 + sc * 8, sB + slot * 16);
    }
  };

  auto compute = [&](int buf) {
    const char* sA = smem + buf * 16384;
    const char* sB = sA + 8192;
    const int c = lane >> 4;
    bf16x8 a[4], b[4];
#pragma unroll
    for (int mi = 0; mi < 4; ++mi) {
      const int row = wm * 64 + mi * 16 + (lane & 15);
      a[mi] = *(const bf16x8*)(sA + row * 64 + ((c ^ (row & 3)) << 4));
    }
#pragma unroll
    for (int ni = 0; ni < 4; ++ni) {
      const int row = wn * 64 + ni * 16 + (lane & 15);
      b[ni] = *(const bf16x8*)(sB + row * 64 + ((c ^ (row & 3)) << 4));
    }
#pragma unroll
    for (int mi = 0; mi < 4; ++mi)
#pragma unroll
      for (int ni = 0; ni < 4; ++ni)
        acc[mi][ni] = __builtin_amdgcn_mfma_f32_16x16x32_bf16(a[mi], b[ni], acc[mi][ni], 0, 0, 0);
  };

  stage(0, 0);
  __syncthreads();
  for (int t = 0; t < nt; ++t) {
    if (t + 1 < nt) stage((t + 1) & 1, t + 1);
    compute(t & 1);
    __syncthreads();
  }

#pragma unroll
  for (int mi = 0; mi < 4; ++mi)
#pragma unroll
    for (int ni = 0; ni < 4; ++ni)
#pragma unroll
      for (int r = 0; r < 4; ++r) {
        const int row = m0 + wm * 64 + mi * 16 + (lane >> 4) * 4 + r;
        const int col = n0 + wn * 64 + ni * 16 + (lane & 15);
        C[(long)row * ldc + col] = (OutT)acc[mi][ni][r];
      }
}

// ---------------- flash attention fwd (R3 structure + K-prefetch) ------------
// grid (32 qtiles, 24 bh); block 256 = 4 waves, wave owns 16 q-rows.
// Swapped QK^T (S^T = K Q^T, lane owns one q-col -> 2-shuffle softmax).
// P in-register (permuted-k mapping). V reg-staged early, paired bf16x2
// swizzled transpose writes (lane-private dwords). K double-buffered in
// registers (next tile prefetched at iteration top). exp2-domain softmax.
__global__ __launch_bounds__(256, 3) void attn_fwd(const bf16* __restrict__ qkv,
                                                   bf16* __restrict__ O) {
  __shared__ __align__(16) char Vs[16384];  // 2 bufs x Vt[64 d][128B kv] swizzled
  const int tid  = threadIdx.x;
  const int lane = tid & 63;
  const int w    = tid >> 6;
  const int l15  = lane & 15;
  const int l4   = lane >> 4;
  const int b    = blockIdx.y / 12;
  const int h    = blockIdx.y % 12;
  const int q0   = blockIdx.x * 64;
  const unsigned base = (unsigned)b * 2048u * 2304u;
  const int h64  = h * 64;
  const unsigned VSTEP = 64u * 2304u;

  // Q fragments, pre-scaled by SCALE*log2(e) = 0.125 * 1.4426950
  bf16x8 qf[2];
  {
    const bf16* qp = qkv + base + (unsigned)(q0 + w * 16 + l15) * 2304u + h64 + l4 * 8;
#pragma unroll
    for (int kk = 0; kk < 2; ++kk) {
      bf16x8 t = *(const bf16x8*)(qp + kk * 32);
#pragma unroll
      for (int j = 0; j < 8; ++j) qf[kk][j] = (bf16)((float)t[j] * 0.18033688f);
    }
  }

  // K row offsets (A-fragments from global; L2/L3-resident)
  unsigned koff[4];
#pragma unroll
  for (int f = 0; f < 4; ++f)
    koff[f] = base + (unsigned)(f * 16 + l15) * 2304u + 768u + h64 + l4 * 8;

  // V staging: thread i -> kv pair p = i&31 (rows 2p,2p+1), d-block dblk = i>>5.
  const int p    = tid & 31;
  const int dblk = tid >> 5;  // [0,8)
  const int pc   = p >> 2;    // chunk = kv>>3
  const int cw   = (p & 3) * 4;
  unsigned voff = base + (unsigned)(2 * p) * 2304u + 1536u + h64 + dblk * 8;

  // write V rows 2p,2p+1 (8 d-elems each) as 8 lane-private bf16x2 dwords
  auto vt_write = [&](char* W, const bf16x8& r0, const bf16x8& r1) {
#pragma unroll
    for (int j = 0; j < 8; ++j) {
      const int d = dblk * 8 + j;  // d&7 == j
      bf16x2 t = { r0[j], r1[j] };
      *(bf16x2*)(W + d * 128 + ((pc ^ j) << 4) + cw) = t;
    }
  };

  float m = -1e30f, lsum = 0.f;
  f32x4 o[4] = {};

  bf16x8 kcA[4][2], kcB[4][2];

  // prologue: V tile 0 -> buf 0; K tile 0 -> kcA
  {
    bf16x8 r0 = *(const bf16x8*)(qkv + voff);
    bf16x8 r1 = *(const bf16x8*)(qkv + voff + 2304);
    voff += VSTEP;
#pragma unroll
    for (int f = 0; f < 4; ++f) {
      kcA[f][0] = *(const bf16x8*)(qkv + koff[f]);
      kcA[f][1] = *(const bf16x8*)(qkv + koff[f] + 32);
      koff[f] += VSTEP;
    }
    vt_write(Vs, r0, r1);
  }
  __syncthreads();

  auto tile_iter = [&](int t, bf16x8 (&kc)[4][2], bf16x8 (&kn)[4][2]) {
    const int buf = t & 1;
    const bool pre = (t < 31);

    // (a) issue next tile's V + K global loads early
    bf16x8 nr0, nr1;
    if (pre) {
      nr0 = *(const bf16x8*)(qkv + voff);
      nr1 = *(const bf16x8*)(qkv + voff + 2304);
      voff += VSTEP;
#pragma unroll
      for (int f = 0; f < 4; ++f) {
        kn[f][0] = *(const bf16x8*)(qkv + koff[f]);
        kn[f][1] = *(const bf16x8*)(qkv + koff[f] + 32);
        koff[f] += VSTEP;
      }
    }

    // (b) S^T = K Q^T : rows = kv (l4*4+r per 16-frag f), cols = q (l15)
    f32x4 s[4];
    __builtin_amdgcn_s_setprio(1);
#pragma unroll
    for (int f = 0; f < 4; ++f) {
      f32x4 acc = {};
      acc = __builtin_amdgcn_mfma_f32_16x16x32_bf16(kc[f][0], qf[0], acc, 0, 0, 0);
      acc = __builtin_amdgcn_mfma_f32_16x16x32_bf16(kc[f][1], qf[1], acc, 0, 0, 0);
      s[f] = acc;
    }
    __builtin_amdgcn_s_setprio(0);

    // (c) softmax (exp2 domain): tile max for this lane's q (=l15)
    float tm = s[0][0];
#pragma unroll
    for (int f = 0; f < 4; ++f)
#pragma unroll
      for (int r = 0; r < 4; ++r) tm = fmaxf(tm, s[f][r]);
    tm = fmaxf(tm, __shfl_xor(tm, 16));
    tm = fmaxf(tm, __shfl_xor(tm, 32));

    // defer-max: rescale only when tile max outgrows running max by >8 (2^8 bound)
    if (__any(tm > m + 8.f)) {
      const float mn = fmaxf(m, tm);
      const float alpha = __builtin_amdgcn_exp2f(m - mn);
      m = mn;
      lsum *= alpha;
      f32x4 av;
#pragma unroll
      for (int r = 0; r < 4; ++r) av[r] = __shfl(alpha, l4 * 4 + r);
#pragma unroll
      for (int fd = 0; fd < 4; ++fd) o[fd] *= av;
    }

    // p = 2^(s - m); lane-local partial row-sum
    float rs = 0.f;
#pragma unroll
    for (int f = 0; f < 4; ++f)
#pragma unroll
      for (int r = 0; r < 4; ++r) {
        const float pv = __builtin_amdgcn_exp2f(s[f][r] - m);
        s[f][r] = pv;
        rs += pv;
      }

    // P A-fragments (k-slot j of mfma kk -> kv = (kk*2+(j>>2))*16 + l4*4 + (j&3))
    bf16x8 pa[2];
#pragma unroll
    for (int kk = 0; kk < 2; ++kk)
#pragma unroll
      for (int j = 0; j < 8; ++j)
        pa[kk][j] = (bf16)s[kk * 2 + (j >> 2)][j & 3];

    // (e) O += P V : B-frags from swizzled Vt with the SAME permuted-kv mapping
    const char* Vb = Vs + buf * 8192;
    const int sub = (l4 & 1) * 8;
    __builtin_amdgcn_s_setprio(1);
#pragma unroll
    for (int kk = 0; kk < 2; ++kk) {
      const int cr0 = kk * 4 + (l4 >> 1);
#pragma unroll
      for (int fd = 0; fd < 4; ++fd) {
        const int d = fd * 16 + l15;
        const char* row = Vb + d * 128;
        bf16x4 lo = *(const bf16x4*)(row + ((cr0 ^ (d & 7)) << 4) + sub);
        bf16x4 hi = *(const bf16x4*)(row + (((cr0 + 2) ^ (d & 7)) << 4) + sub);
        bf16x8 vb = __builtin_shufflevector(lo, hi, 0, 1, 2, 3, 4, 5, 6, 7);
        o[fd] = __builtin_amdgcn_mfma_f32_16x16x32_bf16(pa[kk], vb, o[fd], 0, 0, 0);
      }
    }
    __builtin_amdgcn_s_setprio(0);

    // cross-lane row-sum after PV issue (overlaps matrix pipe)
    rs += __shfl_xor(rs, 16);
    rs += __shfl_xor(rs, 32);
    lsum += rs;

    // (d) late-write next V tile into the other buffer
    if (pre) vt_write(Vs + (buf ^ 1) * 8192, nr0, nr1);

    __syncthreads();
  };

  for (int tt = 0; tt < 16; ++tt) {
    tile_iter(2 * tt,     kcA, kcB);
    tile_iter(2 * tt + 1, kcB, kcA);
  }

  // normalize + store (row = q0 + w*16 + l4*4 + r, col = h64 + fd*16 + l15)
  const float inv = 1.0f / lsum;
  f32x4 iv;
#pragma unroll
  for (int r = 0; r < 4; ++r) iv[r] = __shfl(inv, l4 * 4 + r);
  bf16* op = O + ((long)(b * 2048 + q0 + w * 16 + l4 * 4)) * 768 + h64 + l15;
#pragma unroll
  for (int fd = 0; fd < 4; ++fd)
#pragma unroll
    for (int r = 0; r < 4; ++r)
      op[(long)r * 768 + fd * 16] = (bf16)(o[fd][r] * iv[r]);
}

// ---------------- launch ----------------
extern "C" void kernel_launch(void* const* d_in, const int* in_sizes, int n_in,
                              void* d_out, int out_size, void* d_ws, size_t ws_size,
                              hipStream_t stream) {
  const float* x  = (const float*)d_in[0];
  const float* wq = (const float*)d_in[1];
  const float* wp = (const float*)d_in[2];
  float* out = (float*)d_out;
  char* ws = (char*)d_ws;

  bf16* xb   = (bf16*)(ws + 0);
  bf16* wqb  = (bf16*)(ws + 6291456);
  bf16* wpb  = (bf16*)(ws + 9830400);
  bf16* qkvb = (bf16*)(ws + 11010048);
  bf16* ob   = (bf16*)(ws + 29884416);

  cvt3<<<dim3(1024), dim3(256), 0, stream>>>(x, wq, wp, xb, wqb, wpb);
  // qkv = x @ Wqkv^T : M=4096 N=2304 K=768
  gemm_nt<bf16><<<dim3(576), dim3(256), 0, stream>>>(xb, wqb, qkvb, 768, 768, 768, 2304, 32);
  attn_fwd<<<dim3(32, 24), dim3(256), 0, stream>>>(qkvb, ob);
  // out = attn_out @ Wproj^T : M=4096 N=768 K=768, fp32 out
  gemm_nt<float><<<dim3(192), dim3(256), 0, stream>>>(ob, wpb, out, 768, 768, 768, 768, 32);
}